// Round 9
// baseline (197.929 us; speedup 1.0000x reference)
//
#include <hip/hip_runtime.h>

typedef __attribute__((ext_vector_type(8))) short short8;     // 8 bf16 MFMA operand
typedef __attribute__((ext_vector_type(4))) float f32x4;
typedef __attribute__((ext_vector_type(8))) unsigned short ushort8v;

// B=2, T=2048, D_IN=1024, H=16, D_HEAD=64, D_INNER=1024, M=B*T=4096

__device__ __forceinline__ unsigned short f2bf(float f) {
  union { float f; unsigned int u; } x; x.f = f;
  unsigned int r = x.u + 0x7FFFu + ((x.u >> 16) & 1u);   // RNE
  return (unsigned short)(r >> 16);
}

__device__ __forceinline__ void gload_lds16(const void* g, void* l) {
  __builtin_amdgcn_global_load_lds(
      (const __attribute__((address_space(1))) void*)g,
      (__attribute__((address_space(3))) void*)l, 16, 0, 0);
}

// ---------------- fused prep: bias_init + x->bf16 + 4 weight transposes ----------------
// grid: [0,4096) cvt x | [4096,7168) Wq/Wk/Wv transpose | [7168,7232) Wo | [7232,7488) bias

__global__ __launch_bounds__(256) void prep(
    const float* __restrict__ x,
    const float* __restrict__ Wq, const float* __restrict__ Wk, const float* __restrict__ Wv,
    const float* __restrict__ Wo, const float* __restrict__ bo,
    unsigned short* __restrict__ xb,
    unsigned short* __restrict__ wqt, unsigned short* __restrict__ wkt,
    unsigned short* __restrict__ wvt, unsigned short* __restrict__ wot,
    float* __restrict__ out) {
  __shared__ float tile[32][33];
  int b = blockIdx.x;
  if (b < 4096) {                     // x -> bf16, 4 elems/thread
    int i = (b * 256 + threadIdx.x) * 4;
    float4 f = *(const float4*)(x + i);
    ushort4 o;
    o.x = f2bf(f.x); o.y = f2bf(f.y); o.z = f2bf(f.z); o.w = f2bf(f.w);
    *(ushort4*)(xb + i) = o;
  } else if (b < 7168) {              // W^T for Wq/Wk/Wv (1024x1024)
    int idx = b - 4096;
    int z = idx >> 10, rem = idx & 1023;
    const float* src = (z == 0) ? Wq : (z == 1) ? Wk : Wv;
    unsigned short* dst = (z == 0) ? wqt : (z == 1) ? wkt : wvt;
    int kx = (rem & 31) * 32, ny = (rem >> 5) * 32;
    int tx = threadIdx.x & 31, ty = threadIdx.x >> 5;
    #pragma unroll
    for (int r = 0; r < 32; r += 8)
      tile[ty + r][tx] = src[(size_t)(kx + ty + r) * 1024 + ny + tx];
    __syncthreads();
    #pragma unroll
    for (int r = 0; r < 32; r += 8)
      dst[(size_t)(ny + ty + r) * 1024 + kx + tx] = f2bf(tile[tx][ty + r]);
  } else if (b < 7232) {              // Wo^T (1024x64 -> 64x1024)
    int idx = b - 7168;
    int kx = (idx & 31) * 32, ny = (idx >> 5) * 32;
    int tx = threadIdx.x & 31, ty = threadIdx.x >> 5;
    #pragma unroll
    for (int r = 0; r < 32; r += 8)
      tile[ty + r][tx] = Wo[(size_t)(kx + ty + r) * 64 + ny + tx];
    __syncthreads();
    #pragma unroll
    for (int r = 0; r < 32; r += 8)
      wot[(size_t)(ny + ty + r) * 1024 + kx + tx] = f2bf(tile[tx][ty + r]);
  } else {                            // seed out with bias (out is re-poisoned each call)
    int t = (b - 7232) * 256 + threadIdx.x;  // 65536 float4s
    float4 bi = *(const float4*)(bo + (t & 15) * 4);
    *(float4*)(out + (size_t)t * 4) = bi;
  }
}

// ---------------- QKV projection GEMM, BK=64 with XOR-swizzled staging ----------------
// z=0: Q = x·Wq (scaled 1/32) -> [b][h][t][d]; z=1: K -> [b][h][t][d];
// z=2: V^T computed directly (A=Wv^T, B=x) -> [b][h][d][t]

__global__ __launch_bounds__(256) void qkv_gemm(
    const unsigned short* __restrict__ Xb,
    const unsigned short* __restrict__ Wqt, const unsigned short* __restrict__ Wkt,
    const unsigned short* __restrict__ Wvt,
    unsigned short* __restrict__ Oq, unsigned short* __restrict__ Ok,
    unsigned short* __restrict__ Ovt) {
  constexpr int Kd = 1024;
  __shared__ __align__(16) unsigned short As[128 * 64];
  __shared__ __align__(16) unsigned short Bs[128 * 64];
  int z = blockIdx.z;
  int m0, n0;
  const unsigned short *Arow, *Brow;
  if (z == 2) {
    m0 = blockIdx.y * 128; n0 = blockIdx.x * 128;
    Arow = Wvt; Brow = Xb;
  } else {
    m0 = blockIdx.x * 128; n0 = blockIdx.y * 128;
    Arow = Xb; Brow = (z == 0) ? Wqt : Wkt;
  }
  int tid = threadIdx.x, lane = tid & 63, wave = tid >> 6;
  int wm = wave >> 1, wn = wave & 1;
  int l15 = lane & 15, quad = lane >> 4;
  int swz = l15 & 7;

  f32x4 acc[4][4] = {};

  for (int k0 = 0; k0 < Kd; k0 += 64) {
    __syncthreads();
    #pragma unroll
    for (int r = 0; r < 4; ++r) {
      int i = tid + 256 * r;
      int row = i >> 3, c8 = i & 7;
      int gc8 = c8 ^ (row & 7);
      gload_lds16(Arow + (size_t)(m0 + row) * Kd + k0 + gc8 * 8, &As[i * 8]);
    }
    #pragma unroll
    for (int r = 0; r < 4; ++r) {
      int i = tid + 256 * r;
      int row = i >> 3, c8 = i & 7;
      int gc8 = c8 ^ (row & 7);
      gload_lds16(Brow + (size_t)(n0 + row) * Kd + k0 + gc8 * 8, &Bs[i * 8]);
    }
    __syncthreads();
    short8 af[4][2], bf[4][2];
    #pragma unroll
    for (int s = 0; s < 2; ++s) {
      #pragma unroll
      for (int i = 0; i < 4; ++i)
        af[i][s] = *(const short8*)&As[(wm * 64 + i * 16 + l15) * 64 + (((s << 2) + quad) ^ swz) * 8];
      #pragma unroll
      for (int j = 0; j < 4; ++j)
        bf[j][s] = *(const short8*)&Bs[(wn * 64 + j * 16 + l15) * 64 + (((s << 2) + quad) ^ swz) * 8];
    }
    #pragma unroll
    for (int s = 0; s < 2; ++s)
      #pragma unroll
      for (int i = 0; i < 4; ++i)
        #pragma unroll
        for (int j = 0; j < 4; ++j)
          acc[i][j] = __builtin_amdgcn_mfma_f32_16x16x32_bf16(af[i][s], bf[j][s], acc[i][j], 0, 0, 0);
  }

  if (z == 2) {
    #pragma unroll
    for (int i = 0; i < 4; ++i) {
      int dmbase = m0 + wm * 64 + i * 16 + quad * 4;
      #pragma unroll
      for (int j = 0; j < 4; ++j) {
        int tn = n0 + wn * 64 + j * 16 + l15;
        int b = tn >> 11, t = tn & 2047;
        #pragma unroll
        for (int r = 0; r < 4; ++r) {
          int dm = dmbase + r;
          int h = dm >> 6, d = dm & 63;
          Ovt[(((size_t)(b * 16 + h) * 64 + d) << 11) + t] = f2bf(acc[i][j][r]);
        }
      }
    }
  } else {
    unsigned short* O = (z == 0) ? Oq : Ok;
    float scale = (z == 0) ? 0.03125f : 1.0f;  // 1/sqrt(1024) folded into Q
    #pragma unroll
    for (int i = 0; i < 4; ++i) {
      int mbase = m0 + wm * 64 + i * 16 + quad * 4;
      #pragma unroll
      for (int j = 0; j < 4; ++j) {
        int n = n0 + wn * 64 + j * 16 + l15;
        int h = n >> 6, d = n & 63;
        #pragma unroll
        for (int r = 0; r < 4; ++r) {
          int mm = mbase + r;
          int b = mm >> 11, t = mm & 2047;
          size_t off = (((size_t)(b * 16 + h) * 2048 + t) << 6) + d;
          O[off] = f2bf(acc[i][j][r] * scale);
        }
      }
    }
  }
}

// ---------------- fused causal flash attention v6 ----------------
// attn4 grid (512 blocks x 4 waves = 2048 waves = 2/SIMD, balanced pairs) +
// attn5's V-direct-from-global, PLUS O^T trick: compute O^T = V^T·P^T so
// O's C-layout has q on cols (l15) -> alpha rescale and 1/l finalize are
// per-lane VALU (no shfl; 12 of 16 shfl/iter eliminated), Y write is 4xb64.
// K stays LDS-staged (block-shared, reg prefetch). 16 q/wave.

__global__ __launch_bounds__(256, 2) void attn6(
    const unsigned short* __restrict__ Qg, const unsigned short* __restrict__ Kg,
    const unsigned short* __restrict__ Vtg, unsigned short* __restrict__ Yg) {
  constexpr int T = 2048;
  __shared__ __align__(16) unsigned short Ks[64 * 72];
  __shared__ __align__(16) unsigned short Ps[4][16 * 72];
  int bh = blockIdx.y;
  int pp = (blockIdx.x + blockIdx.y) & 15;   // L2 swizzle over pairs
  int tid = threadIdx.x, lane = tid & 63, wave = tid >> 6;
  int l15 = lane & 15, quad = lane >> 4;
  const unsigned short* Qb = Qg + (size_t)bh * T * 64;
  const unsigned short* Kb = Kg + (size_t)bh * T * 64;
  const unsigned short* Vb = Vtg + (size_t)bh * 64 * T;
  int h = bh & 15, b = bh >> 4;

  for (int phase = 0; phase < 2; ++phase) {
    int qt = phase ? (31 - pp) : pp;          // pair (pp, 31-pp): 33 trips total
    int qw = qt * 64 + wave * 16;

    // Q as B-operand frags (regs): lane n=q(l15), k=d(quad*8+32s)
    short8 qf[2];
    #pragma unroll
    for (int s = 0; s < 2; ++s)
      qf[s] = *(const short8*)(Qb + (size_t)(qw + l15) * 64 + quad * 8 + 32 * s);

    // O^T accumulators: Oacc[jd] C-layout col=l15=q, row=quad*4+r = d within jd*16
    f32x4 Oacc[4] = {};
    float m_run = -__builtin_inff(), l_run = 0.f;

    // prefetch K tile 0 (2 x 16B per thread; 256 threads cover 64x64)
    ushort8v kpre[2];
    #pragma unroll
    for (int r = 0; r < 2; ++r) {
      int i = tid + 256 * r;
      kpre[r] = *(const ushort8v*)(Kb + (size_t)(i >> 3) * 64 + (i & 7) * 8);
    }

    for (int kt = 0; kt <= qt; ++kt) {
      __syncthreads();
      #pragma unroll
      for (int r = 0; r < 2; ++r) {
        int i = tid + 256 * r;
        *(ushort8v*)&Ks[(i >> 3) * 72 + (i & 7) * 8] = kpre[r];
      }
      __syncthreads();
      if (kt < qt) {  // prefetch next K tile while computing
        #pragma unroll
        for (int r = 0; r < 2; ++r) {
          int i = tid + 256 * r;
          kpre[r] = *(const ushort8v*)(Kb + (size_t)((kt + 1) * 64 + (i >> 3)) * 64 + (i & 7) * 8);
        }
      }
      // V^T as A-operand frags direct from global: lane m=d(jd*16+l15), k=tok
      // (issued early; consumed after S-MFMA + softmax -> latency covered, 8 waves/CU TLP)
      short8 vf[4][2];
      #pragma unroll
      for (int jd = 0; jd < 4; ++jd)
        #pragma unroll
        for (int s = 0; s < 2; ++s)
          vf[jd][s] = *(const short8*)(Vb + (size_t)(jd * 16 + l15) * T + kt * 64 + s * 32 + quad * 8);

      // S^T = K·Q^T : rows=tok(64), cols=q(16)
      f32x4 S[4] = {};
      #pragma unroll
      for (int s = 0; s < 2; ++s)
        #pragma unroll
        for (int mi = 0; mi < 4; ++mi) {
          short8 kf = *(const short8*)&Ks[(mi * 16 + l15) * 72 + quad * 8 + 32 * s];
          S[mi] = __builtin_amdgcn_mfma_f32_16x16x32_bf16(kf, qf[s], S[mi], 0, 0, 0);
        }

      if (kt == qt) {  // diagonal tile: mask tok_local > q_local
        int ql = wave * 16 + l15;
        #pragma unroll
        for (int mi = 0; mi < 4; ++mi) {
          int tokl = mi * 16 + quad * 4;
          #pragma unroll
          for (int r = 0; r < 4; ++r)
            if (tokl + r > ql) S[mi][r] = -__builtin_inff();
        }
      }

      // online softmax along tok (2 shfl for max + 2 for sum; nothing else)
      float vmax = -__builtin_inff();
      #pragma unroll
      for (int mi = 0; mi < 4; ++mi)
        #pragma unroll
        for (int r = 0; r < 4; ++r)
          vmax = fmaxf(vmax, S[mi][r]);
      vmax = fmaxf(vmax, __shfl_xor(vmax, 16));
      vmax = fmaxf(vmax, __shfl_xor(vmax, 32));
      float mnew = fmaxf(m_run, vmax);
      float alpha = __expf(m_run - mnew);
      m_run = mnew;
      float rs = 0.f;
      #pragma unroll
      for (int mi = 0; mi < 4; ++mi) {
        float p0 = __expf(S[mi][0] - mnew);
        float p1 = __expf(S[mi][1] - mnew);
        float p2 = __expf(S[mi][2] - mnew);
        float p3 = __expf(S[mi][3] - mnew);
        rs += (p0 + p1) + (p2 + p3);
        union { float f; unsigned int u; } a0{p0}, a1{p1}, a2{p2}, a3{p3};
        uint2 pk;
        pk.x = ((a0.u + 0x8000u) >> 16) | ((a1.u + 0x8000u) & 0xFFFF0000u);
        pk.y = ((a2.u + 0x8000u) >> 16) | ((a3.u + 0x8000u) & 0xFFFF0000u);
        *(uint2*)&Ps[wave][l15 * 72 + mi * 16 + quad * 4] = pk;
      }
      rs += __shfl_xor(rs, 16);
      rs += __shfl_xor(rs, 32);
      l_run = l_run * alpha + rs;

      // rescale O^T: col=q=l15 -> alpha is already per-lane correct. Pure VALU.
      #pragma unroll
      for (int jd = 0; jd < 4; ++jd)
        #pragma unroll
        for (int r = 0; r < 4; ++r)
          Oacc[jd][r] *= alpha;

      // O^T += V^T·P^T  (A=vf global frags, B=P^T from LDS; layout == A-frag)
      #pragma unroll
      for (int s = 0; s < 2; ++s) {
        short8 pf = *(const short8*)&Ps[wave][l15 * 72 + s * 32 + quad * 8];
        #pragma unroll
        for (int jd = 0; jd < 4; ++jd)
          Oacc[jd] = __builtin_amdgcn_mfma_f32_16x16x32_bf16(vf[jd][s], pf, Oacc[jd], 0, 0, 0);
      }
    }

    // finalize: O^T/l per-lane (no shfl); write Y as 4x b64 (q=l15 fixed per lane)
    float linv = 1.f / l_run;
    int q = qw + l15;
    size_t row = (size_t)(b * 2048 + q) * 1024 + h * 64 + quad * 4;
    #pragma unroll
    for (int jd = 0; jd < 4; ++jd) {
      union { float f; unsigned int u; } a0{Oacc[jd][0] * linv}, a1{Oacc[jd][1] * linv},
                                         a2{Oacc[jd][2] * linv}, a3{Oacc[jd][3] * linv};
      uint2 pk;
      pk.x = ((a0.u + 0x7FFFu + ((a0.u >> 16) & 1u)) >> 16) |
             ((a1.u + 0x7FFFu + ((a1.u >> 16) & 1u)) & 0xFFFF0000u);
      pk.y = ((a2.u + 0x7FFFu + ((a2.u >> 16) & 1u)) >> 16) |
             ((a3.u + 0x7FFFu + ((a3.u >> 16) & 1u)) & 0xFFFF0000u);
      *(uint2*)(Yg + row + jd * 16) = pk;
    }
  }
}

// ---------------- out projection: split-K atomics onto bias-seeded out ----------------

__global__ __launch_bounds__(256) void oproj(
    const unsigned short* __restrict__ Y, const unsigned short* __restrict__ Wot,
    float* __restrict__ out) {
  __shared__ __align__(16) unsigned short As[64 * 32];
  __shared__ __align__(16) unsigned short Bs[64 * 32];
  int m0 = blockIdx.x * 64;
  int kbase = blockIdx.y * 256;  // 4-way split-K
  int tid = threadIdx.x, lane = tid & 63, wave = tid >> 6;
  int l15 = lane & 15, quad = lane >> 4;
  f32x4 acc[4] = {};
  for (int k0 = kbase; k0 < kbase + 256; k0 += 32) {
    __syncthreads();
    {
      int row = tid >> 2, c8 = (tid & 3) * 8;
      gload_lds16(Y + (size_t)(m0 + row) * 1024 + k0 + c8, &As[tid * 8]);
      gload_lds16(Wot + (size_t)row * 1024 + k0 + c8, &Bs[tid * 8]);
    }
    __syncthreads();
    short8 af = *(const short8*)&As[(wave * 16 + l15) * 32 + quad * 8];
    #pragma unroll
    for (int j = 0; j < 4; ++j) {
      short8 bf = *(const short8*)&Bs[(j * 16 + l15) * 32 + quad * 8];
      acc[j] = __builtin_amdgcn_mfma_f32_16x16x32_bf16(af, bf, acc[j], 0, 0, 0);
    }
  }
  #pragma unroll
  for (int j = 0; j < 4; ++j) {
    int n = j * 16 + l15;
    #pragma unroll
    for (int r = 0; r < 4; ++r) {
      int m = m0 + wave * 16 + quad * 4 + r;
      atomicAdd(&out[(size_t)m * 64 + n], acc[j][r]);
    }
  }
}

// ---------------- launcher (4 kernels total) ----------------

extern "C" void kernel_launch(void* const* d_in, const int* in_sizes, int n_in,
                              void* d_out, int out_size, void* d_ws, size_t ws_size,
                              hipStream_t stream) {
  const float* x  = (const float*)d_in[0];
  const float* Wq = (const float*)d_in[1];
  const float* Wk = (const float*)d_in[2];
  const float* Wv = (const float*)d_in[3];
  const float* Wo = (const float*)d_in[4];
  const float* bo = (const float*)d_in[5];
  float* out = (float*)d_out;
  char* ws = (char*)d_ws;

  unsigned short* xb  = (unsigned short*)(ws);                       // 8 MB  [4096][1024]
  unsigned short* wqt = (unsigned short*)(ws + (8ull << 20));        // 2 MB  Wq^T
  unsigned short* wkt = (unsigned short*)(ws + (10ull << 20));       // 2 MB
  unsigned short* wvt = (unsigned short*)(ws + (12ull << 20));       // 2 MB
  unsigned short* wot = (unsigned short*)(ws + (14ull << 20));       // 128 KB Wo^T
  unsigned short* q   = (unsigned short*)(ws + (15ull << 20));       // 8 MB  [b][h][t][d]
  unsigned short* k   = (unsigned short*)(ws + (23ull << 20));       // 8 MB  [b][h][t][d]
  unsigned short* vt  = (unsigned short*)(ws + (31ull << 20));       // 8 MB  [b][h][d][t]
  unsigned short* y   = (unsigned short*)(ws + (39ull << 20));       // 8 MB  [4096][1024]

  prep<<<7488, 256, 0, stream>>>(x, Wq, Wk, Wv, Wo, bo, xb, wqt, wkt, wvt, wot, out);
  qkv_gemm<<<dim3(32, 8, 3), 256, 0, stream>>>(xb, wqt, wkt, wvt, q, k, vt);
  attn6<<<dim3(16, 32), 256, 0, stream>>>(q, k, vt, y);
  oproj<<<dim3(64, 4), 256, 0, stream>>>(y, wot, out);
}

// Round 11
// 194.107 us; speedup vs baseline: 1.0197x; 1.0197x over previous
//
#include <hip/hip_runtime.h>

typedef __attribute__((ext_vector_type(8))) short short8;     // 8 bf16 MFMA operand
typedef __attribute__((ext_vector_type(4))) float f32x4;
typedef __attribute__((ext_vector_type(8))) unsigned short ushort8v;

// B=2, T=2048, D_IN=1024, H=16, D_HEAD=64, D_INNER=1024, M=B*T=4096

__device__ __forceinline__ unsigned short f2bf(float f) {
  union { float f; unsigned int u; } x; x.f = f;
  unsigned int r = x.u + 0x7FFFu + ((x.u >> 16) & 1u);   // RNE
  return (unsigned short)(r >> 16);
}

__device__ __forceinline__ void gload_lds16(const void* g, void* l) {
  __builtin_amdgcn_global_load_lds(
      (const __attribute__((address_space(1))) void*)g,
      (__attribute__((address_space(3))) void*)l, 16, 0, 0);
}

// ---------------- fused prep: bias_init + x->bf16 + 4 weight transposes ----------------
// grid: [0,4096) cvt x | [4096,7168) Wq/Wk/Wv transpose | [7168,7232) Wo | [7232,7488) bias

__global__ __launch_bounds__(256) void prep(
    const float* __restrict__ x,
    const float* __restrict__ Wq, const float* __restrict__ Wk, const float* __restrict__ Wv,
    const float* __restrict__ Wo, const float* __restrict__ bo,
    unsigned short* __restrict__ xb,
    unsigned short* __restrict__ wqt, unsigned short* __restrict__ wkt,
    unsigned short* __restrict__ wvt, unsigned short* __restrict__ wot,
    float* __restrict__ out) {
  __shared__ float tile[32][33];
  int b = blockIdx.x;
  if (b < 4096) {                     // x -> bf16, 4 elems/thread
    int i = (b * 256 + threadIdx.x) * 4;
    float4 f = *(const float4*)(x + i);
    ushort4 o;
    o.x = f2bf(f.x); o.y = f2bf(f.y); o.z = f2bf(f.z); o.w = f2bf(f.w);
    *(ushort4*)(xb + i) = o;
  } else if (b < 7168) {              // W^T for Wq/Wk/Wv (1024x1024)
    int idx = b - 4096;
    int z = idx >> 10, rem = idx & 1023;
    const float* src = (z == 0) ? Wq : (z == 1) ? Wk : Wv;
    unsigned short* dst = (z == 0) ? wqt : (z == 1) ? wkt : wvt;
    int kx = (rem & 31) * 32, ny = (rem >> 5) * 32;
    int tx = threadIdx.x & 31, ty = threadIdx.x >> 5;
    #pragma unroll
    for (int r = 0; r < 32; r += 8)
      tile[ty + r][tx] = src[(size_t)(kx + ty + r) * 1024 + ny + tx];
    __syncthreads();
    #pragma unroll
    for (int r = 0; r < 32; r += 8)
      dst[(size_t)(ny + ty + r) * 1024 + kx + tx] = f2bf(tile[tx][ty + r]);
  } else if (b < 7232) {              // Wo^T (1024x64 -> 64x1024)
    int idx = b - 7168;
    int kx = (idx & 31) * 32, ny = (idx >> 5) * 32;
    int tx = threadIdx.x & 31, ty = threadIdx.x >> 5;
    #pragma unroll
    for (int r = 0; r < 32; r += 8)
      tile[ty + r][tx] = Wo[(size_t)(kx + ty + r) * 64 + ny + tx];
    __syncthreads();
    #pragma unroll
    for (int r = 0; r < 32; r += 8)
      wot[(size_t)(ny + ty + r) * 1024 + kx + tx] = f2bf(tile[tx][ty + r]);
  } else {                            // seed out with bias (out is re-poisoned each call)
    int t = (b - 7232) * 256 + threadIdx.x;  // 65536 float4s
    float4 bi = *(const float4*)(bo + (t & 15) * 4);
    *(float4*)(out + (size_t)t * 4) = bi;
  }
}

// ---------------- QKV projection GEMM, BK=64 with XOR-swizzled staging ----------------
// z=0: Q = x·Wq (scaled 1/32) -> [b][h][t][d]; z=1: K -> [b][h][t][d];
// z=2: V^T computed directly (A=Wv^T, B=x) -> [b][h][d][t]

__global__ __launch_bounds__(256) void qkv_gemm(
    const unsigned short* __restrict__ Xb,
    const unsigned short* __restrict__ Wqt, const unsigned short* __restrict__ Wkt,
    const unsigned short* __restrict__ Wvt,
    unsigned short* __restrict__ Oq, unsigned short* __restrict__ Ok,
    unsigned short* __restrict__ Ovt) {
  constexpr int Kd = 1024;
  __shared__ __align__(16) unsigned short As[128 * 64];
  __shared__ __align__(16) unsigned short Bs[128 * 64];
  int z = blockIdx.z;
  int m0, n0;
  const unsigned short *Arow, *Brow;
  if (z == 2) {
    m0 = blockIdx.y * 128; n0 = blockIdx.x * 128;
    Arow = Wvt; Brow = Xb;
  } else {
    m0 = blockIdx.x * 128; n0 = blockIdx.y * 128;
    Arow = Xb; Brow = (z == 0) ? Wqt : Wkt;
  }
  int tid = threadIdx.x, lane = tid & 63, wave = tid >> 6;
  int wm = wave >> 1, wn = wave & 1;
  int l15 = lane & 15, quad = lane >> 4;
  int swz = l15 & 7;

  f32x4 acc[4][4] = {};

  for (int k0 = 0; k0 < Kd; k0 += 64) {
    __syncthreads();
    #pragma unroll
    for (int r = 0; r < 4; ++r) {
      int i = tid + 256 * r;
      int row = i >> 3, c8 = i & 7;
      int gc8 = c8 ^ (row & 7);
      gload_lds16(Arow + (size_t)(m0 + row) * Kd + k0 + gc8 * 8, &As[i * 8]);
    }
    #pragma unroll
    for (int r = 0; r < 4; ++r) {
      int i = tid + 256 * r;
      int row = i >> 3, c8 = i & 7;
      int gc8 = c8 ^ (row & 7);
      gload_lds16(Brow + (size_t)(n0 + row) * Kd + k0 + gc8 * 8, &Bs[i * 8]);
    }
    __syncthreads();
    short8 af[4][2], bf[4][2];
    #pragma unroll
    for (int s = 0; s < 2; ++s) {
      #pragma unroll
      for (int i = 0; i < 4; ++i)
        af[i][s] = *(const short8*)&As[(wm * 64 + i * 16 + l15) * 64 + (((s << 2) + quad) ^ swz) * 8];
      #pragma unroll
      for (int j = 0; j < 4; ++j)
        bf[j][s] = *(const short8*)&Bs[(wn * 64 + j * 16 + l15) * 64 + (((s << 2) + quad) ^ swz) * 8];
    }
    #pragma unroll
    for (int s = 0; s < 2; ++s)
      #pragma unroll
      for (int i = 0; i < 4; ++i)
        #pragma unroll
        for (int j = 0; j < 4; ++j)
          acc[i][j] = __builtin_amdgcn_mfma_f32_16x16x32_bf16(af[i][s], bf[j][s], acc[i][j], 0, 0, 0);
  }

  if (z == 2) {
    #pragma unroll
    for (int i = 0; i < 4; ++i) {
      int dmbase = m0 + wm * 64 + i * 16 + quad * 4;
      #pragma unroll
      for (int j = 0; j < 4; ++j) {
        int tn = n0 + wn * 64 + j * 16 + l15;
        int b = tn >> 11, t = tn & 2047;
        #pragma unroll
        for (int r = 0; r < 4; ++r) {
          int dm = dmbase + r;
          int h = dm >> 6, d = dm & 63;
          Ovt[(((size_t)(b * 16 + h) * 64 + d) << 11) + t] = f2bf(acc[i][j][r]);
        }
      }
    }
  } else {
    unsigned short* O = (z == 0) ? Oq : Ok;
    float scale = (z == 0) ? 0.03125f : 1.0f;  // 1/sqrt(1024) folded into Q
    #pragma unroll
    for (int i = 0; i < 4; ++i) {
      int mbase = m0 + wm * 64 + i * 16 + quad * 4;
      #pragma unroll
      for (int j = 0; j < 4; ++j) {
        int n = n0 + wn * 64 + j * 16 + l15;
        int h = n >> 6, d = n & 63;
        #pragma unroll
        for (int r = 0; r < 4; ++r) {
          int mm = mbase + r;
          int b = mm >> 11, t = mm & 2047;
          size_t off = (((size_t)(b * 16 + h) * 2048 + t) << 6) + d;
          O[off] = f2bf(acc[i][j][r] * scale);
        }
      }
    }
  }
}

// ---------------- fused causal flash attention v7 ----------------
// attn6 with ONE structural fix: V-frag loads are issued BEFORE the next-tile
// K prefetch. vmcnt is in-order (m135): consuming vf previously forced a full
// drain of the younger-issued kpre loads -> next-tile K latency sat on every
// iteration's critical path. Now vf waits leave kpre in flight (drained only
// at the next __syncthreads, a full iteration later). O^T = V^T·P^T layout:
// alpha/1/l finalize per-lane, no shfl; Y write 4xb64. 16 q/wave, balanced
// pairs (p,31-p), 512x4-wave grid = 2 waves/SIMD.

__global__ __launch_bounds__(256, 2) void attn7(
    const unsigned short* __restrict__ Qg, const unsigned short* __restrict__ Kg,
    const unsigned short* __restrict__ Vtg, unsigned short* __restrict__ Yg) {
  constexpr int T = 2048;
  __shared__ __align__(16) unsigned short Ks[64 * 72];
  __shared__ __align__(16) unsigned short Ps[4][16 * 72];
  int bh = blockIdx.y;
  int pp = (blockIdx.x + blockIdx.y) & 15;   // L2 swizzle over pairs
  int tid = threadIdx.x, lane = tid & 63, wave = tid >> 6;
  int l15 = lane & 15, quad = lane >> 4;
  const unsigned short* Qb = Qg + (size_t)bh * T * 64;
  const unsigned short* Kb = Kg + (size_t)bh * T * 64;
  const unsigned short* Vb = Vtg + (size_t)bh * 64 * T;
  int h = bh & 15, b = bh >> 4;

  for (int phase = 0; phase < 2; ++phase) {
    int qt = phase ? (31 - pp) : pp;          // pair (pp, 31-pp): 33 trips total
    int qw = qt * 64 + wave * 16;

    // Q as B-operand frags (regs): lane n=q(l15), k=d(quad*8+32s)
    short8 qf[2];
    #pragma unroll
    for (int s = 0; s < 2; ++s)
      qf[s] = *(const short8*)(Qb + (size_t)(qw + l15) * 64 + quad * 8 + 32 * s);

    // O^T accumulators: Oacc[jd] C-layout col=l15=q, row=quad*4+r = d within jd*16
    f32x4 Oacc[4] = {};
    float m_run = -__builtin_inff(), l_run = 0.f;

    // prefetch K tile 0 (2 x 16B per thread; 256 threads cover 64x64)
    ushort8v kpre[2];
    #pragma unroll
    for (int r = 0; r < 2; ++r) {
      int i = tid + 256 * r;
      kpre[r] = *(const ushort8v*)(Kb + (size_t)(i >> 3) * 64 + (i & 7) * 8);
    }

    for (int kt = 0; kt <= qt; ++kt) {
      __syncthreads();
      #pragma unroll
      for (int r = 0; r < 2; ++r) {
        int i = tid + 256 * r;
        *(ushort8v*)&Ks[(i >> 3) * 72 + (i & 7) * 8] = kpre[r];
      }
      __syncthreads();

      // V^T as A-operand frags direct from global, issued FIRST (oldest in
      // vmcnt order): lane m=d(jd*16+l15), k=tok. Consumed after S+softmax.
      short8 vf[4][2];
      #pragma unroll
      for (int jd = 0; jd < 4; ++jd)
        #pragma unroll
        for (int s = 0; s < 2; ++s)
          vf[jd][s] = *(const short8*)(Vb + (size_t)(jd * 16 + l15) * T + kt * 64 + s * 32 + quad * 8);

      if (kt < qt) {  // next-tile K prefetch issued AFTER vf (younger: stays in flight)
        #pragma unroll
        for (int r = 0; r < 2; ++r) {
          int i = tid + 256 * r;
          kpre[r] = *(const ushort8v*)(Kb + (size_t)((kt + 1) * 64 + (i >> 3)) * 64 + (i & 7) * 8);
        }
      }

      // S^T = K·Q^T : rows=tok(64), cols=q(16)
      f32x4 S[4] = {};
      #pragma unroll
      for (int s = 0; s < 2; ++s)
        #pragma unroll
        for (int mi = 0; mi < 4; ++mi) {
          short8 kf = *(const short8*)&Ks[(mi * 16 + l15) * 72 + quad * 8 + 32 * s];
          S[mi] = __builtin_amdgcn_mfma_f32_16x16x32_bf16(kf, qf[s], S[mi], 0, 0, 0);
        }

      if (kt == qt) {  // diagonal tile: mask tok_local > q_local
        int ql = wave * 16 + l15;
        #pragma unroll
        for (int mi = 0; mi < 4; ++mi) {
          int tokl = mi * 16 + quad * 4;
          #pragma unroll
          for (int r = 0; r < 4; ++r)
            if (tokl + r > ql) S[mi][r] = -__builtin_inff();
        }
      }

      // online softmax along tok (2 shfl for max + 2 for sum; nothing else)
      float vmax = -__builtin_inff();
      #pragma unroll
      for (int mi = 0; mi < 4; ++mi)
        #pragma unroll
        for (int r = 0; r < 4; ++r)
          vmax = fmaxf(vmax, S[mi][r]);
      vmax = fmaxf(vmax, __shfl_xor(vmax, 16));
      vmax = fmaxf(vmax, __shfl_xor(vmax, 32));
      float mnew = fmaxf(m_run, vmax);
      float alpha = __expf(m_run - mnew);
      m_run = mnew;
      float rs = 0.f;
      #pragma unroll
      for (int mi = 0; mi < 4; ++mi) {
        float p0 = __expf(S[mi][0] - mnew);
        float p1 = __expf(S[mi][1] - mnew);
        float p2 = __expf(S[mi][2] - mnew);
        float p3 = __expf(S[mi][3] - mnew);
        rs += (p0 + p1) + (p2 + p3);
        union { float f; unsigned int u; } a0{p0}, a1{p1}, a2{p2}, a3{p3};
        uint2 pk;
        pk.x = ((a0.u + 0x8000u) >> 16) | ((a1.u + 0x8000u) & 0xFFFF0000u);
        pk.y = ((a2.u + 0x8000u) >> 16) | ((a3.u + 0x8000u) & 0xFFFF0000u);
        *(uint2*)&Ps[wave][l15 * 72 + mi * 16 + quad * 4] = pk;
      }
      rs += __shfl_xor(rs, 16);
      rs += __shfl_xor(rs, 32);
      l_run = l_run * alpha + rs;

      // rescale O^T: col=q=l15 -> alpha is already per-lane correct. Pure VALU.
      #pragma unroll
      for (int jd = 0; jd < 4; ++jd)
        #pragma unroll
        for (int r = 0; r < 4; ++r)
          Oacc[jd][r] *= alpha;

      // O^T += V^T·P^T  (A=vf global frags [wait vmcnt leaves kpre in flight],
      // B=P^T from LDS; layout == A-frag)
      #pragma unroll
      for (int s = 0; s < 2; ++s) {
        short8 pf = *(const short8*)&Ps[wave][l15 * 72 + s * 32 + quad * 8];
        #pragma unroll
        for (int jd = 0; jd < 4; ++jd)
          Oacc[jd] = __builtin_amdgcn_mfma_f32_16x16x32_bf16(vf[jd][s], pf, Oacc[jd], 0, 0, 0);
      }
    }

    // finalize: O^T/l per-lane (no shfl); write Y as 4x b64 (q=l15 fixed per lane)
    float linv = 1.f / l_run;
    int q = qw + l15;
    size_t row = (size_t)(b * 2048 + q) * 1024 + h * 64 + quad * 4;
    #pragma unroll
    for (int jd = 0; jd < 4; ++jd) {
      union { float f; unsigned int u; } a0{Oacc[jd][0] * linv}, a1{Oacc[jd][1] * linv},
                                         a2{Oacc[jd][2] * linv}, a3{Oacc[jd][3] * linv};
      uint2 pk;
      pk.x = ((a0.u + 0x7FFFu + ((a0.u >> 16) & 1u)) >> 16) |
             ((a1.u + 0x7FFFu + ((a1.u >> 16) & 1u)) & 0xFFFF0000u);
      pk.y = ((a2.u + 0x7FFFu + ((a2.u >> 16) & 1u)) >> 16) |
             ((a3.u + 0x7FFFu + ((a3.u >> 16) & 1u)) & 0xFFFF0000u);
      *(uint2*)(Yg + row + jd * 16) = pk;
    }
  }
}

// ---------------- out projection: split-K atomics onto bias-seeded out ----------------

__global__ __launch_bounds__(256) void oproj(
    const unsigned short* __restrict__ Y, const unsigned short* __restrict__ Wot,
    float* __restrict__ out) {
  __shared__ __align__(16) unsigned short As[64 * 32];
  __shared__ __align__(16) unsigned short Bs[64 * 32];
  int m0 = blockIdx.x * 64;
  int kbase = blockIdx.y * 256;  // 4-way split-K
  int tid = threadIdx.x, lane = tid & 63, wave = tid >> 6;
  int l15 = lane & 15, quad = lane >> 4;
  f32x4 acc[4] = {};
  for (int k0 = kbase; k0 < kbase + 256; k0 += 32) {
    __syncthreads();
    {
      int row = tid >> 2, c8 = (tid & 3) * 8;
      gload_lds16(Y + (size_t)(m0 + row) * 1024 + k0 + c8, &As[tid * 8]);
      gload_lds16(Wot + (size_t)row * 1024 + k0 + c8, &Bs[tid * 8]);
    }
    __syncthreads();
    short8 af = *(const short8*)&As[(wave * 16 + l15) * 32 + quad * 8];
    #pragma unroll
    for (int j = 0; j < 4; ++j) {
      short8 bf = *(const short8*)&Bs[(j * 16 + l15) * 32 + quad * 8];
      acc[j] = __builtin_amdgcn_mfma_f32_16x16x32_bf16(af, bf, acc[j], 0, 0, 0);
    }
  }
  #pragma unroll
  for (int j = 0; j < 4; ++j) {
    int n = j * 16 + l15;
    #pragma unroll
    for (int r = 0; r < 4; ++r) {
      int m = m0 + wave * 16 + quad * 4 + r;
      atomicAdd(&out[(size_t)m * 64 + n], acc[j][r]);
    }
  }
}

// ---------------- launcher (4 kernels total) ----------------

extern "C" void kernel_launch(void* const* d_in, const int* in_sizes, int n_in,
                              void* d_out, int out_size, void* d_ws, size_t ws_size,
                              hipStream_t stream) {
  const float* x  = (const float*)d_in[0];
  const float* Wq = (const float*)d_in[1];
  const float* Wk = (const float*)d_in[2];
  const float* Wv = (const float*)d_in[3];
  const float* Wo = (const float*)d_in[4];
  const float* bo = (const float*)d_in[5];
  float* out = (float*)d_out;
  char* ws = (char*)d_ws;

  unsigned short* xb  = (unsigned short*)(ws);                       // 8 MB  [4096][1024]
  unsigned short* wqt = (unsigned short*)(ws + (8ull << 20));        // 2 MB  Wq^T
  unsigned short* wkt = (unsigned short*)(ws + (10ull << 20));       // 2 MB
  unsigned short* wvt = (unsigned short*)(ws + (12ull << 20));       // 2 MB
  unsigned short* wot = (unsigned short*)(ws + (14ull << 20));       // 128 KB Wo^T
  unsigned short* q   = (unsigned short*)(ws + (15ull << 20));       // 8 MB  [b][h][t][d]
  unsigned short* k   = (unsigned short*)(ws + (23ull << 20));       // 8 MB  [b][h][t][d]
  unsigned short* vt  = (unsigned short*)(ws + (31ull << 20));       // 8 MB  [b][h][d][t]
  unsigned short* y   = (unsigned short*)(ws + (39ull << 20));       // 8 MB  [4096][1024]

  prep<<<7488, 256, 0, stream>>>(x, Wq, Wk, Wv, Wo, bo, xb, wqt, wkt, wvt, wot, out);
  qkv_gemm<<<dim3(32, 8, 3), 256, 0, stream>>>(xb, wqt, wkt, wvt, q, k, vt);
  attn7<<<dim3(16, 32), 256, 0, stream>>>(q, k, vt, y);
  oproj<<<dim3(64, 4), 256, 0, stream>>>(y, wot, out);
}

// Round 12
// 177.590 us; speedup vs baseline: 1.1145x; 1.0930x over previous
//
#include <hip/hip_runtime.h>

typedef __attribute__((ext_vector_type(8))) short short8;     // 8 bf16 MFMA operand
typedef __attribute__((ext_vector_type(4))) float f32x4;
typedef __attribute__((ext_vector_type(8))) unsigned short ushort8v;

// B=2, T=2048, D_IN=1024, H=16, D_HEAD=64, D_INNER=1024, M=B*T=4096

__device__ __forceinline__ unsigned short f2bf(float f) {
  union { float f; unsigned int u; } x; x.f = f;
  unsigned int r = x.u + 0x7FFFu + ((x.u >> 16) & 1u);   // RNE
  return (unsigned short)(r >> 16);
}

__device__ __forceinline__ void gload_lds16(const void* g, void* l) {
  __builtin_amdgcn_global_load_lds(
      (const __attribute__((address_space(1))) void*)g,
      (__attribute__((address_space(3))) void*)l, 16, 0, 0);
}

// ---------------- fused prep: bias_init + x->bf16 + 4 weight transposes ----------------
// grid: [0,4096) cvt x | [4096,7168) Wq/Wk/Wv transpose | [7168,7232) Wo | [7232,7488) bias

__global__ __launch_bounds__(256) void prep(
    const float* __restrict__ x,
    const float* __restrict__ Wq, const float* __restrict__ Wk, const float* __restrict__ Wv,
    const float* __restrict__ Wo, const float* __restrict__ bo,
    unsigned short* __restrict__ xb,
    unsigned short* __restrict__ wqt, unsigned short* __restrict__ wkt,
    unsigned short* __restrict__ wvt, unsigned short* __restrict__ wot,
    float* __restrict__ out) {
  __shared__ float tile[32][33];
  int b = blockIdx.x;
  if (b < 4096) {                     // x -> bf16, 4 elems/thread
    int i = (b * 256 + threadIdx.x) * 4;
    float4 f = *(const float4*)(x + i);
    ushort4 o;
    o.x = f2bf(f.x); o.y = f2bf(f.y); o.z = f2bf(f.z); o.w = f2bf(f.w);
    *(ushort4*)(xb + i) = o;
  } else if (b < 7168) {              // W^T for Wq/Wk/Wv (1024x1024)
    int idx = b - 4096;
    int z = idx >> 10, rem = idx & 1023;
    const float* src = (z == 0) ? Wq : (z == 1) ? Wk : Wv;
    unsigned short* dst = (z == 0) ? wqt : (z == 1) ? wkt : wvt;
    int kx = (rem & 31) * 32, ny = (rem >> 5) * 32;
    int tx = threadIdx.x & 31, ty = threadIdx.x >> 5;
    #pragma unroll
    for (int r = 0; r < 32; r += 8)
      tile[ty + r][tx] = src[(size_t)(kx + ty + r) * 1024 + ny + tx];
    __syncthreads();
    #pragma unroll
    for (int r = 0; r < 32; r += 8)
      dst[(size_t)(ny + ty + r) * 1024 + kx + tx] = f2bf(tile[tx][ty + r]);
  } else if (b < 7232) {              // Wo^T (1024x64 -> 64x1024)
    int idx = b - 7168;
    int kx = (idx & 31) * 32, ny = (idx >> 5) * 32;
    int tx = threadIdx.x & 31, ty = threadIdx.x >> 5;
    #pragma unroll
    for (int r = 0; r < 32; r += 8)
      tile[ty + r][tx] = Wo[(size_t)(kx + ty + r) * 64 + ny + tx];
    __syncthreads();
    #pragma unroll
    for (int r = 0; r < 32; r += 8)
      wot[(size_t)(ny + ty + r) * 1024 + kx + tx] = f2bf(tile[tx][ty + r]);
  } else {                            // seed out with bias (out is re-poisoned each call)
    int t = (b - 7232) * 256 + threadIdx.x;  // 65536 float4s
    float4 bi = *(const float4*)(bo + (t & 15) * 4);
    *(float4*)(out + (size_t)t * 4) = bi;
  }
}

// ---------------- QKV projection GEMM, BK=64 with XOR-swizzled staging ----------------
// z=0: Q = x·Wq (scaled 1/32) -> [b][h][t][d]; z=1: K -> [b][h][t][d];
// z=2: V^T computed directly (A=Wv^T, B=x) -> [b][h][d][t]

__global__ __launch_bounds__(256) void qkv_gemm(
    const unsigned short* __restrict__ Xb,
    const unsigned short* __restrict__ Wqt, const unsigned short* __restrict__ Wkt,
    const unsigned short* __restrict__ Wvt,
    unsigned short* __restrict__ Oq, unsigned short* __restrict__ Ok,
    unsigned short* __restrict__ Ovt) {
  constexpr int Kd = 1024;
  __shared__ __align__(16) unsigned short As[128 * 64];
  __shared__ __align__(16) unsigned short Bs[128 * 64];
  int z = blockIdx.z;
  int m0, n0;
  const unsigned short *Arow, *Brow;
  if (z == 2) {
    m0 = blockIdx.y * 128; n0 = blockIdx.x * 128;
    Arow = Wvt; Brow = Xb;
  } else {
    m0 = blockIdx.x * 128; n0 = blockIdx.y * 128;
    Arow = Xb; Brow = (z == 0) ? Wqt : Wkt;
  }
  int tid = threadIdx.x, lane = tid & 63, wave = tid >> 6;
  int wm = wave >> 1, wn = wave & 1;
  int l15 = lane & 15, quad = lane >> 4;
  int swz = l15 & 7;

  f32x4 acc[4][4] = {};

  for (int k0 = 0; k0 < Kd; k0 += 64) {
    __syncthreads();
    #pragma unroll
    for (int r = 0; r < 4; ++r) {
      int i = tid + 256 * r;
      int row = i >> 3, c8 = i & 7;
      int gc8 = c8 ^ (row & 7);
      gload_lds16(Arow + (size_t)(m0 + row) * Kd + k0 + gc8 * 8, &As[i * 8]);
    }
    #pragma unroll
    for (int r = 0; r < 4; ++r) {
      int i = tid + 256 * r;
      int row = i >> 3, c8 = i & 7;
      int gc8 = c8 ^ (row & 7);
      gload_lds16(Brow + (size_t)(n0 + row) * Kd + k0 + gc8 * 8, &Bs[i * 8]);
    }
    __syncthreads();
    short8 af[4][2], bf[4][2];
    #pragma unroll
    for (int s = 0; s < 2; ++s) {
      #pragma unroll
      for (int i = 0; i < 4; ++i)
        af[i][s] = *(const short8*)&As[(wm * 64 + i * 16 + l15) * 64 + (((s << 2) + quad) ^ swz) * 8];
      #pragma unroll
      for (int j = 0; j < 4; ++j)
        bf[j][s] = *(const short8*)&Bs[(wn * 64 + j * 16 + l15) * 64 + (((s << 2) + quad) ^ swz) * 8];
    }
    #pragma unroll
    for (int s = 0; s < 2; ++s)
      #pragma unroll
      for (int i = 0; i < 4; ++i)
        #pragma unroll
        for (int j = 0; j < 4; ++j)
          acc[i][j] = __builtin_amdgcn_mfma_f32_16x16x32_bf16(af[i][s], bf[j][s], acc[i][j], 0, 0, 0);
  }

  if (z == 2) {
    #pragma unroll
    for (int i = 0; i < 4; ++i) {
      int dmbase = m0 + wm * 64 + i * 16 + quad * 4;
      #pragma unroll
      for (int j = 0; j < 4; ++j) {
        int tn = n0 + wn * 64 + j * 16 + l15;
        int b = tn >> 11, t = tn & 2047;
        #pragma unroll
        for (int r = 0; r < 4; ++r) {
          int dm = dmbase + r;
          int h = dm >> 6, d = dm & 63;
          Ovt[(((size_t)(b * 16 + h) * 64 + d) << 11) + t] = f2bf(acc[i][j][r]);
        }
      }
    }
  } else {
    unsigned short* O = (z == 0) ? Oq : Ok;
    float scale = (z == 0) ? 0.03125f : 1.0f;  // 1/sqrt(1024) folded into Q
    #pragma unroll
    for (int i = 0; i < 4; ++i) {
      int mbase = m0 + wm * 64 + i * 16 + quad * 4;
      #pragma unroll
      for (int j = 0; j < 4; ++j) {
        int n = n0 + wn * 64 + j * 16 + l15;
        int h = n >> 6, d = n & 63;
        #pragma unroll
        for (int r = 0; r < 4; ++r) {
          int mm = mbase + r;
          int b = mm >> 11, t = mm & 2047;
          size_t off = (((size_t)(b * 16 + h) * 2048 + t) << 6) + d;
          O[off] = f2bf(acc[i][j][r] * scale);
        }
      }
    }
  }
}

// ---------------- fused causal flash attention v8 ----------------
// 32 q/wave (2x MFMA per K/V LDS frag read — the LDS pipe is the measured
// bottleneck), 4 waves x 128-row q-tiles, 512 single-tile blocks = 2048 waves
// (2/SIMD). Balance via dispatch-order complements: blocks [0,256) = heavy
// tiles (qt=8+t), [256,512) = light (qt=7-t); round-robin dispatch puts i and
// i+256 on one CU -> 34 trips/CU uniform, same bh both slots (L2 reuse).
// K AND V^T both LDS-staged (attn4's proven reg-prefetch; V-from-global
// regressed in attn6/7). O^T = V^T·P^T epilogue: per-lane alpha, b64 Y-write.

__global__ __launch_bounds__(256, 2) void attn8(
    const unsigned short* __restrict__ Qg, const unsigned short* __restrict__ Kg,
    const unsigned short* __restrict__ Vtg, unsigned short* __restrict__ Yg) {
  constexpr int T = 2048;
  __shared__ __align__(16) unsigned short Ks[64 * 72];   // [tok][d]
  __shared__ __align__(16) unsigned short Vs[64 * 72];   // [d][tok]
  __shared__ __align__(16) unsigned short Ps[4][32 * 72];
  int bi = blockIdx.x;
  int half = bi >> 8, idx = bi & 255;
  int bh = idx & 31;
  int t8 = idx >> 5;                       // [0,8)
  int qt = half ? (7 - t8) : (8 + t8);     // complement pairs sum trips to 34
  int tid = threadIdx.x, lane = tid & 63, wave = tid >> 6;
  int l15 = lane & 15, quad = lane >> 4;
  const unsigned short* Qb = Qg + (size_t)bh * T * 64;
  const unsigned short* Kb = Kg + (size_t)bh * T * 64;
  const unsigned short* Vb = Vtg + (size_t)bh * 64 * T;
  int h = bh & 15, b = bh >> 4;
  int qw = qt * 128 + wave * 32;

  // Q as B-operand frags (regs): lane n=q(jq*16+l15), k=d(quad*8+32s)
  short8 qf[2][2];
  #pragma unroll
  for (int jq = 0; jq < 2; ++jq)
    #pragma unroll
    for (int s = 0; s < 2; ++s)
      qf[jq][s] = *(const short8*)(Qb + (size_t)(qw + jq * 16 + l15) * 64 + quad * 8 + 32 * s);

  // O^T accumulators [jq][jd]: C-layout col=l15=q (within jq), row=quad*4+r=d (within jd)
  f32x4 Oacc[2][4] = {};
  float m_run[2] = {-__builtin_inff(), -__builtin_inff()};
  float l_run[2] = {0.f, 0.f};

  int ntrip = 2 * qt + 2;   // k-tiles of 64 covering tokens [0, 128qt+128)

  // prefetch tile 0 (2 x 16B per thread per buffer; 256 threads cover 64x64)
  ushort8v kpre[2], vpre[2];
  #pragma unroll
  for (int r = 0; r < 2; ++r) {
    int i = tid + 256 * r;
    kpre[r] = *(const ushort8v*)(Kb + (size_t)(i >> 3) * 64 + (i & 7) * 8);
    vpre[r] = *(const ushort8v*)(Vb + (size_t)(i >> 3) * T + (i & 7) * 8);
  }

  for (int kt = 0; kt < ntrip; ++kt) {
    __syncthreads();
    #pragma unroll
    for (int r = 0; r < 2; ++r) {
      int i = tid + 256 * r;
      *(ushort8v*)&Ks[(i >> 3) * 72 + (i & 7) * 8] = kpre[r];
      *(ushort8v*)&Vs[(i >> 3) * 72 + (i & 7) * 8] = vpre[r];
    }
    __syncthreads();
    if (kt + 1 < ntrip) {  // prefetch next tile while computing (attn4 pattern)
      #pragma unroll
      for (int r = 0; r < 2; ++r) {
        int i = tid + 256 * r;
        kpre[r] = *(const ushort8v*)(Kb + (size_t)((kt + 1) * 64 + (i >> 3)) * 64 + (i & 7) * 8);
        vpre[r] = *(const ushort8v*)(Vb + (size_t)(i >> 3) * T + (kt + 1) * 64 + (i & 7) * 8);
      }
    }

    if (kt * 64 > qw + 31) continue;  // this wave's rows all precede this k-tile (fully masked)

    // S^T = K·Q^T : rows=tok(64), cols=q(32); K frags shared across jq
    f32x4 S[4][2] = {};
    #pragma unroll
    for (int s = 0; s < 2; ++s)
      #pragma unroll
      for (int mi = 0; mi < 4; ++mi) {
        short8 kf = *(const short8*)&Ks[(mi * 16 + l15) * 72 + quad * 8 + 32 * s];
        #pragma unroll
        for (int jq = 0; jq < 2; ++jq)
          S[mi][jq] = __builtin_amdgcn_mfma_f32_16x16x32_bf16(kf, qf[jq][s], S[mi][jq], 0, 0, 0);
      }

    if (kt * 64 + 63 > qw) {  // overlap tile: mask tok > q
      #pragma unroll
      for (int mi = 0; mi < 4; ++mi) {
        int tok = kt * 64 + mi * 16 + quad * 4;
        #pragma unroll
        for (int jq = 0; jq < 2; ++jq) {
          int q = qw + jq * 16 + l15;
          #pragma unroll
          for (int r = 0; r < 4; ++r)
            if (tok + r > q) S[mi][jq][r] = -__builtin_inff();
        }
      }
    }

    // online softmax along tok per jq block
    float alpha[2];
    #pragma unroll
    for (int jq = 0; jq < 2; ++jq) {
      float vmax = -__builtin_inff();
      #pragma unroll
      for (int mi = 0; mi < 4; ++mi)
        #pragma unroll
        for (int r = 0; r < 4; ++r)
          vmax = fmaxf(vmax, S[mi][jq][r]);
      vmax = fmaxf(vmax, __shfl_xor(vmax, 16));
      vmax = fmaxf(vmax, __shfl_xor(vmax, 32));
      float mnew = fmaxf(m_run[jq], vmax);
      alpha[jq] = __expf(m_run[jq] - mnew);
      m_run[jq] = mnew;
      float rs = 0.f;
      #pragma unroll
      for (int mi = 0; mi < 4; ++mi) {
        float p0 = __expf(S[mi][jq][0] - mnew);
        float p1 = __expf(S[mi][jq][1] - mnew);
        float p2 = __expf(S[mi][jq][2] - mnew);
        float p3 = __expf(S[mi][jq][3] - mnew);
        rs += (p0 + p1) + (p2 + p3);
        union { float f; unsigned int u; } a0{p0}, a1{p1}, a2{p2}, a3{p3};
        uint2 pk;
        pk.x = ((a0.u + 0x8000u) >> 16) | ((a1.u + 0x8000u) & 0xFFFF0000u);
        pk.y = ((a2.u + 0x8000u) >> 16) | ((a3.u + 0x8000u) & 0xFFFF0000u);
        *(uint2*)&Ps[wave][(jq * 16 + l15) * 72 + mi * 16 + quad * 4] = pk;
      }
      rs += __shfl_xor(rs, 16);
      rs += __shfl_xor(rs, 32);
      l_run[jq] = l_run[jq] * alpha[jq] + rs;
    }

    // rescale O^T: col=q=l15 within jq -> alpha per-lane, pure VALU
    #pragma unroll
    for (int jq = 0; jq < 2; ++jq)
      #pragma unroll
      for (int jd = 0; jd < 4; ++jd)
        #pragma unroll
        for (int r = 0; r < 4; ++r)
          Oacc[jq][jd][r] *= alpha[jq];

    // O^T += V^T·P^T  (A=Vs frags [d][tok], B=P^T from Ps; V frags shared across jq)
    #pragma unroll
    for (int s = 0; s < 2; ++s) {
      short8 vfr[4];
      #pragma unroll
      for (int jd = 0; jd < 4; ++jd)
        vfr[jd] = *(const short8*)&Vs[(jd * 16 + l15) * 72 + s * 32 + quad * 8];
      #pragma unroll
      for (int jq = 0; jq < 2; ++jq) {
        short8 pf = *(const short8*)&Ps[wave][(jq * 16 + l15) * 72 + s * 32 + quad * 8];
        #pragma unroll
        for (int jd = 0; jd < 4; ++jd)
          Oacc[jq][jd] = __builtin_amdgcn_mfma_f32_16x16x32_bf16(vfr[jd], pf, Oacc[jq][jd], 0, 0, 0);
      }
    }
  }

  // finalize: O^T/l per-lane (no shfl); Y write b64 per jd (d = jd*16+quad*4..+3)
  #pragma unroll
  for (int jq = 0; jq < 2; ++jq) {
    float linv = 1.f / l_run[jq];
    int q = qw + jq * 16 + l15;
    size_t row = (size_t)(b * 2048 + q) * 1024 + h * 64 + quad * 4;
    #pragma unroll
    for (int jd = 0; jd < 4; ++jd) {
      union { float f; unsigned int u; } a0{Oacc[jq][jd][0] * linv}, a1{Oacc[jq][jd][1] * linv},
                                         a2{Oacc[jq][jd][2] * linv}, a3{Oacc[jq][jd][3] * linv};
      uint2 pk;
      pk.x = ((a0.u + 0x7FFFu + ((a0.u >> 16) & 1u)) >> 16) |
             ((a1.u + 0x7FFFu + ((a1.u >> 16) & 1u)) & 0xFFFF0000u);
      pk.y = ((a2.u + 0x7FFFu + ((a2.u >> 16) & 1u)) >> 16) |
             ((a3.u + 0x7FFFu + ((a3.u >> 16) & 1u)) & 0xFFFF0000u);
      *(uint2*)(Yg + row + jd * 16) = pk;
    }
  }
}

// ---------------- out projection: split-K atomics onto bias-seeded out ----------------

__global__ __launch_bounds__(256) void oproj(
    const unsigned short* __restrict__ Y, const unsigned short* __restrict__ Wot,
    float* __restrict__ out) {
  __shared__ __align__(16) unsigned short As[64 * 32];
  __shared__ __align__(16) unsigned short Bs[64 * 32];
  int m0 = blockIdx.x * 64;
  int kbase = blockIdx.y * 256;  // 4-way split-K
  int tid = threadIdx.x, lane = tid & 63, wave = tid >> 6;
  int l15 = lane & 15, quad = lane >> 4;
  f32x4 acc[4] = {};
  for (int k0 = kbase; k0 < kbase + 256; k0 += 32) {
    __syncthreads();
    {
      int row = tid >> 2, c8 = (tid & 3) * 8;
      gload_lds16(Y + (size_t)(m0 + row) * 1024 + k0 + c8, &As[tid * 8]);
      gload_lds16(Wot + (size_t)row * 1024 + k0 + c8, &Bs[tid * 8]);
    }
    __syncthreads();
    short8 af = *(const short8*)&As[(wave * 16 + l15) * 32 + quad * 8];
    #pragma unroll
    for (int j = 0; j < 4; ++j) {
      short8 bf = *(const short8*)&Bs[(j * 16 + l15) * 32 + quad * 8];
      acc[j] = __builtin_amdgcn_mfma_f32_16x16x32_bf16(af, bf, acc[j], 0, 0, 0);
    }
  }
  #pragma unroll
  for (int j = 0; j < 4; ++j) {
    int n = j * 16 + l15;
    #pragma unroll
    for (int r = 0; r < 4; ++r) {
      int m = m0 + wave * 16 + quad * 4 + r;
      atomicAdd(&out[(size_t)m * 64 + n], acc[j][r]);
    }
  }
}

// ---------------- launcher (4 kernels total) ----------------

extern "C" void kernel_launch(void* const* d_in, const int* in_sizes, int n_in,
                              void* d_out, int out_size, void* d_ws, size_t ws_size,
                              hipStream_t stream) {
  const float* x  = (const float*)d_in[0];
  const float* Wq = (const float*)d_in[1];
  const float* Wk = (const float*)d_in[2];
  const float* Wv = (const float*)d_in[3];
  const float* Wo = (const float*)d_in[4];
  const float* bo = (const float*)d_in[5];
  float* out = (float*)d_out;
  char* ws = (char*)d_ws;

  unsigned short* xb  = (unsigned short*)(ws);                       // 8 MB  [4096][1024]
  unsigned short* wqt = (unsigned short*)(ws + (8ull << 20));        // 2 MB  Wq^T
  unsigned short* wkt = (unsigned short*)(ws + (10ull << 20));       // 2 MB
  unsigned short* wvt = (unsigned short*)(ws + (12ull << 20));       // 2 MB
  unsigned short* wot = (unsigned short*)(ws + (14ull << 20));       // 128 KB Wo^T
  unsigned short* q   = (unsigned short*)(ws + (15ull << 20));       // 8 MB  [b][h][t][d]
  unsigned short* k   = (unsigned short*)(ws + (23ull << 20));       // 8 MB  [b][h][t][d]
  unsigned short* vt  = (unsigned short*)(ws + (31ull << 20));       // 8 MB  [b][h][d][t]
  unsigned short* y   = (unsigned short*)(ws + (39ull << 20));       // 8 MB  [4096][1024]

  prep<<<7488, 256, 0, stream>>>(x, Wq, Wk, Wv, Wo, bo, xb, wqt, wkt, wvt, wot, out);
  qkv_gemm<<<dim3(32, 8, 3), 256, 0, stream>>>(xb, wqt, wkt, wvt, q, k, vt);
  attn8<<<512, 256, 0, stream>>>(q, k, vt, y);
  oproj<<<dim3(64, 4), 256, 0, stream>>>(y, wot, out);
}

// Round 13
// 158.759 us; speedup vs baseline: 1.2467x; 1.1186x over previous
//
#include <hip/hip_runtime.h>

typedef __attribute__((ext_vector_type(8))) short short8;     // 8 bf16 MFMA operand
typedef __attribute__((ext_vector_type(4))) float f32x4;
typedef __attribute__((ext_vector_type(8))) unsigned short ushort8v;

// B=2, T=2048, D_IN=1024, H=16, D_HEAD=64, D_INNER=1024, M=B*T=4096

__device__ __forceinline__ unsigned short f2bf(float f) {
  union { float f; unsigned int u; } x; x.f = f;
  unsigned int r = x.u + 0x7FFFu + ((x.u >> 16) & 1u);   // RNE
  return (unsigned short)(r >> 16);
}

__device__ __forceinline__ void gload_lds16(const void* g, void* l) {
  __builtin_amdgcn_global_load_lds(
      (const __attribute__((address_space(1))) void*)g,
      (__attribute__((address_space(3))) void*)l, 16, 0, 0);
}

// ---------------- fused prep: bias_init + x->bf16 + 4 weight transposes ----------------
// grid: [0,4096) cvt x | [4096,7168) Wq/Wk/Wv transpose | [7168,7232) Wo | [7232,7488) bias

__global__ __launch_bounds__(256) void prep(
    const float* __restrict__ x,
    const float* __restrict__ Wq, const float* __restrict__ Wk, const float* __restrict__ Wv,
    const float* __restrict__ Wo, const float* __restrict__ bo,
    unsigned short* __restrict__ xb,
    unsigned short* __restrict__ wqt, unsigned short* __restrict__ wkt,
    unsigned short* __restrict__ wvt, unsigned short* __restrict__ wot,
    float* __restrict__ out) {
  __shared__ float tile[32][33];
  int b = blockIdx.x;
  if (b < 4096) {                     // x -> bf16, 4 elems/thread
    int i = (b * 256 + threadIdx.x) * 4;
    float4 f = *(const float4*)(x + i);
    ushort4 o;
    o.x = f2bf(f.x); o.y = f2bf(f.y); o.z = f2bf(f.z); o.w = f2bf(f.w);
    *(ushort4*)(xb + i) = o;
  } else if (b < 7168) {              // W^T for Wq/Wk/Wv (1024x1024)
    int idx = b - 4096;
    int z = idx >> 10, rem = idx & 1023;
    const float* src = (z == 0) ? Wq : (z == 1) ? Wk : Wv;
    unsigned short* dst = (z == 0) ? wqt : (z == 1) ? wkt : wvt;
    int kx = (rem & 31) * 32, ny = (rem >> 5) * 32;
    int tx = threadIdx.x & 31, ty = threadIdx.x >> 5;
    #pragma unroll
    for (int r = 0; r < 32; r += 8)
      tile[ty + r][tx] = src[(size_t)(kx + ty + r) * 1024 + ny + tx];
    __syncthreads();
    #pragma unroll
    for (int r = 0; r < 32; r += 8)
      dst[(size_t)(ny + ty + r) * 1024 + kx + tx] = f2bf(tile[tx][ty + r]);
  } else if (b < 7232) {              // Wo^T (1024x64 -> 64x1024)
    int idx = b - 7168;
    int kx = (idx & 31) * 32, ny = (idx >> 5) * 32;
    int tx = threadIdx.x & 31, ty = threadIdx.x >> 5;
    #pragma unroll
    for (int r = 0; r < 32; r += 8)
      tile[ty + r][tx] = Wo[(size_t)(kx + ty + r) * 64 + ny + tx];
    __syncthreads();
    #pragma unroll
    for (int r = 0; r < 32; r += 8)
      wot[(size_t)(ny + ty + r) * 1024 + kx + tx] = f2bf(tile[tx][ty + r]);
  } else {                            // seed out with bias (out is re-poisoned each call)
    int t = (b - 7232) * 256 + threadIdx.x;  // 65536 float4s
    float4 bi = *(const float4*)(bo + (t & 15) * 4);
    *(float4*)(out + (size_t)t * 4) = bi;
  }
}

// ---------------- QKV projection GEMM, BK=64, XOR-swizzled staging ----------------
// Operand roles chosen so the 4 in-lane C regs are consecutive in the OUTPUT's
// fastest dim -> epilogue packs 2xbf16 pairs and stores 16 b64 (was 64 b16).
// z=0/1: A=W^T (m over d_inner), B=x (n over tokens) -> D[d][t]; in-lane r = consecutive d.
// z=2:   A=x (m over tokens), B=Wv^T (n over d_inner) -> D[t][d]; in-lane r = consecutive t.

__global__ __launch_bounds__(256) void qkv_gemm(
    const unsigned short* __restrict__ Xb,
    const unsigned short* __restrict__ Wqt, const unsigned short* __restrict__ Wkt,
    const unsigned short* __restrict__ Wvt,
    unsigned short* __restrict__ Oq, unsigned short* __restrict__ Ok,
    unsigned short* __restrict__ Ovt) {
  constexpr int Kd = 1024;
  __shared__ __align__(16) unsigned short As[128 * 64];
  __shared__ __align__(16) unsigned short Bs[128 * 64];
  int z = blockIdx.z;
  int m0, n0;
  const unsigned short *Arow, *Brow;
  if (z == 2) {          // m tokens (32 tiles), n d_inner (8 tiles)
    m0 = blockIdx.x * 128; n0 = blockIdx.y * 128;
    Arow = Xb; Brow = Wvt;
  } else {               // m d_inner (8 tiles), n tokens (32 tiles)
    m0 = blockIdx.y * 128; n0 = blockIdx.x * 128;
    Arow = (z == 0) ? Wqt : Wkt; Brow = Xb;
  }
  int tid = threadIdx.x, lane = tid & 63, wave = tid >> 6;
  int wm = wave >> 1, wn = wave & 1;
  int l15 = lane & 15, quad = lane >> 4;
  int swz = l15 & 7;

  f32x4 acc[4][4] = {};

  for (int k0 = 0; k0 < Kd; k0 += 64) {
    __syncthreads();
    #pragma unroll
    for (int r = 0; r < 4; ++r) {
      int i = tid + 256 * r;
      int row = i >> 3, c8 = i & 7;
      int gc8 = c8 ^ (row & 7);
      gload_lds16(Arow + (size_t)(m0 + row) * Kd + k0 + gc8 * 8, &As[i * 8]);
    }
    #pragma unroll
    for (int r = 0; r < 4; ++r) {
      int i = tid + 256 * r;
      int row = i >> 3, c8 = i & 7;
      int gc8 = c8 ^ (row & 7);
      gload_lds16(Brow + (size_t)(n0 + row) * Kd + k0 + gc8 * 8, &Bs[i * 8]);
    }
    __syncthreads();
    short8 af[4][2], bf[4][2];
    #pragma unroll
    for (int s = 0; s < 2; ++s) {
      #pragma unroll
      for (int i = 0; i < 4; ++i)
        af[i][s] = *(const short8*)&As[(wm * 64 + i * 16 + l15) * 64 + (((s << 2) + quad) ^ swz) * 8];
      #pragma unroll
      for (int j = 0; j < 4; ++j)
        bf[j][s] = *(const short8*)&Bs[(wn * 64 + j * 16 + l15) * 64 + (((s << 2) + quad) ^ swz) * 8];
    }
    #pragma unroll
    for (int s = 0; s < 2; ++s)
      #pragma unroll
      for (int i = 0; i < 4; ++i)
        #pragma unroll
        for (int j = 0; j < 4; ++j)
          acc[i][j] = __builtin_amdgcn_mfma_f32_16x16x32_bf16(af[i][s], bf[j][s], acc[i][j], 0, 0, 0);
  }

  if (z == 2) {
    // D[t][d] -> Vt[(b*16+h)*64+d][t], pack 4 consecutive t per lane -> b64
    #pragma unroll
    for (int i = 0; i < 4; ++i) {
      int tbase = m0 + wm * 64 + i * 16 + quad * 4;
      int b = tbase >> 11, tt = tbase & 2047;
      #pragma unroll
      for (int j = 0; j < 4; ++j) {
        int dm = n0 + wn * 64 + j * 16 + l15;
        int h = dm >> 6, d = dm & 63;
        unsigned int u0 = f2bf(acc[i][j][0]), u1 = f2bf(acc[i][j][1]);
        unsigned int u2 = f2bf(acc[i][j][2]), u3 = f2bf(acc[i][j][3]);
        uint2 pk; pk.x = u0 | (u1 << 16); pk.y = u2 | (u3 << 16);
        *(uint2*)(Ovt + (((size_t)(b * 16 + h) * 64 + d) << 11) + tt) = pk;
      }
    }
  } else {
    // D[d][t] -> O[(b*16+h)*2048+t][d], pack 4 consecutive d per lane -> b64
    unsigned short* O = (z == 0) ? Oq : Ok;
    float scale = (z == 0) ? 0.03125f : 1.0f;  // 1/sqrt(1024) folded into Q
    #pragma unroll
    for (int i = 0; i < 4; ++i) {
      int dmbase = m0 + wm * 64 + i * 16 + quad * 4;
      int h = dmbase >> 6, d0 = dmbase & 63;
      #pragma unroll
      for (int j = 0; j < 4; ++j) {
        int t = n0 + wn * 64 + j * 16 + l15;
        int b = t >> 11, tt = t & 2047;
        unsigned int u0 = f2bf(acc[i][j][0] * scale), u1 = f2bf(acc[i][j][1] * scale);
        unsigned int u2 = f2bf(acc[i][j][2] * scale), u3 = f2bf(acc[i][j][3] * scale);
        uint2 pk; pk.x = u0 | (u1 << 16); pk.y = u2 | (u3 << 16);
        *(uint2*)(O + (((size_t)(b * 16 + h) * 2048 + tt) << 6) + d0) = pk;
      }
    }
  }
}

// ---------------- fused causal flash attention v9: merged dual-tile waves ----------------
// Each wave owns 16 q in light tile qtA=pp AND 16 q in heavy tile qtB=31-pp.
// One k-sweep: loop1 (kt<=qtA) processes BOTH against the shared staged tile
// (K/V frag reads feed 2 MFMAs -> 12 LDS-cyc/MFMA); loop2 (qtA<kt<=qtB) jq1
// only. Per-CU work constant across complement pairs (pp,15-pp) co-resident
// via bh=bx, pp = by<8 ? by : 23-by (ids i,i+256 share bh, complement pp).
// O^T=V^T·P^T epilogue: per-lane alpha, b64 Y writes. 512 blocks x 4 waves.

__global__ __launch_bounds__(256, 2) void attn9(
    const unsigned short* __restrict__ Qg, const unsigned short* __restrict__ Kg,
    const unsigned short* __restrict__ Vtg, unsigned short* __restrict__ Yg) {
  constexpr int T = 2048;
  __shared__ __align__(16) unsigned short Ks[64 * 72];   // [tok][d]
  __shared__ __align__(16) unsigned short Vs[64 * 72];   // [d][tok]
  __shared__ __align__(16) unsigned short Ps[4][32 * 72];
  int bh = blockIdx.x;
  int by = blockIdx.y;
  int pp = (by < 8) ? by : 23 - by;        // blocks (bx,by),(bx,by+8): same bh, complement pp
  int qtA = pp, qtB = 31 - pp;             // light, heavy 64-row q-tiles
  int tid = threadIdx.x, lane = tid & 63, wave = tid >> 6;
  int l15 = lane & 15, quad = lane >> 4;
  const unsigned short* Qb = Qg + (size_t)bh * T * 64;
  const unsigned short* Kb = Kg + (size_t)bh * T * 64;
  const unsigned short* Vb = Vtg + (size_t)bh * 64 * T;
  int h = bh & 15, b = bh >> 4;
  int qw[2] = {qtA * 64 + wave * 16, qtB * 64 + wave * 16};

  // Q as B-operand frags (regs): lane n=q(l15), k=d(quad*8+32s)
  short8 qf[2][2];
  #pragma unroll
  for (int jq = 0; jq < 2; ++jq)
    #pragma unroll
    for (int s = 0; s < 2; ++s)
      qf[jq][s] = *(const short8*)(Qb + (size_t)(qw[jq] + l15) * 64 + quad * 8 + 32 * s);

  // O^T accumulators [jq][jd]: C col=l15=q, row=quad*4+r = d within jd*16
  f32x4 Oacc[2][4] = {};
  float m_run[2] = {-__builtin_inff(), -__builtin_inff()};
  float l_run[2] = {0.f, 0.f};

  // prefetch tile 0
  ushort8v kpre[2], vpre[2];
  #pragma unroll
  for (int r = 0; r < 2; ++r) {
    int i = tid + 256 * r;
    kpre[r] = *(const ushort8v*)(Kb + (size_t)(i >> 3) * 64 + (i & 7) * 8);
    vpre[r] = *(const ushort8v*)(Vb + (size_t)(i >> 3) * T + (i & 7) * 8);
  }

  // ---- loop 1: kt in [0, qtA] — both jq active (dual MFMA per frag read) ----
  for (int kt = 0; kt <= qtA; ++kt) {
    __syncthreads();
    #pragma unroll
    for (int r = 0; r < 2; ++r) {
      int i = tid + 256 * r;
      *(ushort8v*)&Ks[(i >> 3) * 72 + (i & 7) * 8] = kpre[r];
      *(ushort8v*)&Vs[(i >> 3) * 72 + (i & 7) * 8] = vpre[r];
    }
    __syncthreads();
    {  // prefetch kt+1 (always exists: kt+1 <= qtA+1 <= qtB)
      #pragma unroll
      for (int r = 0; r < 2; ++r) {
        int i = tid + 256 * r;
        kpre[r] = *(const ushort8v*)(Kb + (size_t)((kt + 1) * 64 + (i >> 3)) * 64 + (i & 7) * 8);
        vpre[r] = *(const ushort8v*)(Vb + (size_t)(i >> 3) * T + (kt + 1) * 64 + (i & 7) * 8);
      }
    }

    f32x4 S[4][2] = {};
    #pragma unroll
    for (int s = 0; s < 2; ++s)
      #pragma unroll
      for (int mi = 0; mi < 4; ++mi) {
        short8 kf = *(const short8*)&Ks[(mi * 16 + l15) * 72 + quad * 8 + 32 * s];
        #pragma unroll
        for (int jq = 0; jq < 2; ++jq)
          S[mi][jq] = __builtin_amdgcn_mfma_f32_16x16x32_bf16(kf, qf[jq][s], S[mi][jq], 0, 0, 0);
      }

    if (kt == qtA) {  // diagonal of light tile: mask jq0 (jq1 rows are all beyond this tile)
      int ql = wave * 16 + l15;
      #pragma unroll
      for (int mi = 0; mi < 4; ++mi) {
        int tokl = mi * 16 + quad * 4;
        #pragma unroll
        for (int r = 0; r < 4; ++r)
          if (tokl + r > ql) S[mi][0][r] = -__builtin_inff();
      }
    }

    float alpha[2];
    #pragma unroll
    for (int jq = 0; jq < 2; ++jq) {
      float vmax = -__builtin_inff();
      #pragma unroll
      for (int mi = 0; mi < 4; ++mi)
        #pragma unroll
        for (int r = 0; r < 4; ++r)
          vmax = fmaxf(vmax, S[mi][jq][r]);
      vmax = fmaxf(vmax, __shfl_xor(vmax, 16));
      vmax = fmaxf(vmax, __shfl_xor(vmax, 32));
      float mnew = fmaxf(m_run[jq], vmax);
      alpha[jq] = __expf(m_run[jq] - mnew);
      m_run[jq] = mnew;
      float rs = 0.f;
      #pragma unroll
      for (int mi = 0; mi < 4; ++mi) {
        float p0 = __expf(S[mi][jq][0] - mnew);
        float p1 = __expf(S[mi][jq][1] - mnew);
        float p2 = __expf(S[mi][jq][2] - mnew);
        float p3 = __expf(S[mi][jq][3] - mnew);
        rs += (p0 + p1) + (p2 + p3);
        union { float f; unsigned int u; } a0{p0}, a1{p1}, a2{p2}, a3{p3};
        uint2 pk;
        pk.x = ((a0.u + 0x8000u) >> 16) | ((a1.u + 0x8000u) & 0xFFFF0000u);
        pk.y = ((a2.u + 0x8000u) >> 16) | ((a3.u + 0x8000u) & 0xFFFF0000u);
        *(uint2*)&Ps[wave][(jq * 16 + l15) * 72 + mi * 16 + quad * 4] = pk;
      }
      rs += __shfl_xor(rs, 16);
      rs += __shfl_xor(rs, 32);
      l_run[jq] = l_run[jq] * alpha[jq] + rs;
    }

    #pragma unroll
    for (int jq = 0; jq < 2; ++jq)
      #pragma unroll
      for (int jd = 0; jd < 4; ++jd)
        #pragma unroll
        for (int r = 0; r < 4; ++r)
          Oacc[jq][jd][r] *= alpha[jq];

    #pragma unroll
    for (int s = 0; s < 2; ++s) {
      short8 vfr[4];
      #pragma unroll
      for (int jd = 0; jd < 4; ++jd)
        vfr[jd] = *(const short8*)&Vs[(jd * 16 + l15) * 72 + s * 32 + quad * 8];
      #pragma unroll
      for (int jq = 0; jq < 2; ++jq) {
        short8 pf = *(const short8*)&Ps[wave][(jq * 16 + l15) * 72 + s * 32 + quad * 8];
        #pragma unroll
        for (int jd = 0; jd < 4; ++jd)
          Oacc[jq][jd] = __builtin_amdgcn_mfma_f32_16x16x32_bf16(vfr[jd], pf, Oacc[jq][jd], 0, 0, 0);
      }
    }
  }

  // ---- loop 2: kt in (qtA, qtB] — heavy tile only ----
  for (int kt = qtA + 1; kt <= qtB; ++kt) {
    __syncthreads();
    #pragma unroll
    for (int r = 0; r < 2; ++r) {
      int i = tid + 256 * r;
      *(ushort8v*)&Ks[(i >> 3) * 72 + (i & 7) * 8] = kpre[r];
      *(ushort8v*)&Vs[(i >> 3) * 72 + (i & 7) * 8] = vpre[r];
    }
    __syncthreads();
    if (kt < qtB) {
      #pragma unroll
      for (int r = 0; r < 2; ++r) {
        int i = tid + 256 * r;
        kpre[r] = *(const ushort8v*)(Kb + (size_t)((kt + 1) * 64 + (i >> 3)) * 64 + (i & 7) * 8);
        vpre[r] = *(const ushort8v*)(Vb + (size_t)(i >> 3) * T + (kt + 1) * 64 + (i & 7) * 8);
      }
    }

    f32x4 S[4] = {};
    #pragma unroll
    for (int s = 0; s < 2; ++s)
      #pragma unroll
      for (int mi = 0; mi < 4; ++mi) {
        short8 kf = *(const short8*)&Ks[(mi * 16 + l15) * 72 + quad * 8 + 32 * s];
        S[mi] = __builtin_amdgcn_mfma_f32_16x16x32_bf16(kf, qf[1][s], S[mi], 0, 0, 0);
      }

    if (kt == qtB) {  // diagonal of heavy tile
      int ql = wave * 16 + l15;
      #pragma unroll
      for (int mi = 0; mi < 4; ++mi) {
        int tokl = mi * 16 + quad * 4;
        #pragma unroll
        for (int r = 0; r < 4; ++r)
          if (tokl + r > ql) S[mi][r] = -__builtin_inff();
      }
    }

    float vmax = -__builtin_inff();
    #pragma unroll
    for (int mi = 0; mi < 4; ++mi)
      #pragma unroll
      for (int r = 0; r < 4; ++r)
        vmax = fmaxf(vmax, S[mi][r]);
    vmax = fmaxf(vmax, __shfl_xor(vmax, 16));
    vmax = fmaxf(vmax, __shfl_xor(vmax, 32));
    float mnew = fmaxf(m_run[1], vmax);
    float alpha = __expf(m_run[1] - mnew);
    m_run[1] = mnew;
    float rs = 0.f;
    #pragma unroll
    for (int mi = 0; mi < 4; ++mi) {
      float p0 = __expf(S[mi][0] - mnew);
      float p1 = __expf(S[mi][1] - mnew);
      float p2 = __expf(S[mi][2] - mnew);
      float p3 = __expf(S[mi][3] - mnew);
      rs += (p0 + p1) + (p2 + p3);
      union { float f; unsigned int u; } a0{p0}, a1{p1}, a2{p2}, a3{p3};
      uint2 pk;
      pk.x = ((a0.u + 0x8000u) >> 16) | ((a1.u + 0x8000u) & 0xFFFF0000u);
      pk.y = ((a2.u + 0x8000u) >> 16) | ((a3.u + 0x8000u) & 0xFFFF0000u);
      *(uint2*)&Ps[wave][(16 + l15) * 72 + mi * 16 + quad * 4] = pk;
    }
    rs += __shfl_xor(rs, 16);
    rs += __shfl_xor(rs, 32);
    l_run[1] = l_run[1] * alpha + rs;

    #pragma unroll
    for (int jd = 0; jd < 4; ++jd)
      #pragma unroll
      for (int r = 0; r < 4; ++r)
        Oacc[1][jd][r] *= alpha;

    #pragma unroll
    for (int s = 0; s < 2; ++s) {
      short8 pf = *(const short8*)&Ps[wave][(16 + l15) * 72 + s * 32 + quad * 8];
      #pragma unroll
      for (int jd = 0; jd < 4; ++jd) {
        short8 vfr = *(const short8*)&Vs[(jd * 16 + l15) * 72 + s * 32 + quad * 8];
        Oacc[1][jd] = __builtin_amdgcn_mfma_f32_16x16x32_bf16(vfr, pf, Oacc[1][jd], 0, 0, 0);
      }
    }
  }

  // finalize both tiles: O^T/l per-lane; Y write b64 per jd
  #pragma unroll
  for (int jq = 0; jq < 2; ++jq) {
    float linv = 1.f / l_run[jq];
    int q = qw[jq] + l15;
    size_t row = (size_t)(b * 2048 + q) * 1024 + h * 64 + quad * 4;
    #pragma unroll
    for (int jd = 0; jd < 4; ++jd) {
      unsigned int u0 = f2bf(Oacc[jq][jd][0] * linv), u1 = f2bf(Oacc[jq][jd][1] * linv);
      unsigned int u2 = f2bf(Oacc[jq][jd][2] * linv), u3 = f2bf(Oacc[jq][jd][3] * linv);
      uint2 pk; pk.x = u0 | (u1 << 16); pk.y = u2 | (u3 << 16);
      *(uint2*)(Yg + row + jd * 16) = pk;
    }
  }
}

// ---------------- out projection: split-K atomics onto bias-seeded out ----------------

__global__ __launch_bounds__(256) void oproj(
    const unsigned short* __restrict__ Y, const unsigned short* __restrict__ Wot,
    float* __restrict__ out) {
  __shared__ __align__(16) unsigned short As[64 * 32];
  __shared__ __align__(16) unsigned short Bs[64 * 32];
  int m0 = blockIdx.x * 64;
  int kbase = blockIdx.y * 256;  // 4-way split-K
  int tid = threadIdx.x, lane = tid & 63, wave = tid >> 6;
  int l15 = lane & 15, quad = lane >> 4;
  f32x4 acc[4] = {};
  for (int k0 = kbase; k0 < kbase + 256; k0 += 32) {
    __syncthreads();
    {
      int row = tid >> 2, c8 = (tid & 3) * 8;
      gload_lds16(Y + (size_t)(m0 + row) * 1024 + k0 + c8, &As[tid * 8]);
      gload_lds16(Wot + (size_t)row * 1024 + k0 + c8, &Bs[tid * 8]);
    }
    __syncthreads();
    short8 af = *(const short8*)&As[(wave * 16 + l15) * 32 + quad * 8];
    #pragma unroll
    for (int j = 0; j < 4; ++j) {
      short8 bf = *(const short8*)&Bs[(j * 16 + l15) * 32 + quad * 8];
      acc[j] = __builtin_amdgcn_mfma_f32_16x16x32_bf16(af, bf, acc[j], 0, 0, 0);
    }
  }
  #pragma unroll
  for (int j = 0; j < 4; ++j) {
    int n = j * 16 + l15;
    #pragma unroll
    for (int r = 0; r < 4; ++r) {
      int m = m0 + wave * 16 + quad * 4 + r;
      atomicAdd(&out[(size_t)m * 64 + n], acc[j][r]);
    }
  }
}

// ---------------- launcher (4 kernels total) ----------------

extern "C" void kernel_launch(void* const* d_in, const int* in_sizes, int n_in,
                              void* d_out, int out_size, void* d_ws, size_t ws_size,
                              hipStream_t stream) {
  const float* x  = (const float*)d_in[0];
  const float* Wq = (const float*)d_in[1];
  const float* Wk = (const float*)d_in[2];
  const float* Wv = (const float*)d_in[3];
  const float* Wo = (const float*)d_in[4];
  const float* bo = (const float*)d_in[5];
  float* out = (float*)d_out;
  char* ws = (char*)d_ws;

  unsigned short* xb  = (unsigned short*)(ws);                       // 8 MB  [4096][1024]
  unsigned short* wqt = (unsigned short*)(ws + (8ull << 20));        // 2 MB  Wq^T
  unsigned short* wkt = (unsigned short*)(ws + (10ull << 20));       // 2 MB
  unsigned short* wvt = (unsigned short*)(ws + (12ull << 20));       // 2 MB
  unsigned short* wot = (unsigned short*)(ws + (14ull << 20));       // 128 KB Wo^T
  unsigned short* q   = (unsigned short*)(ws + (15ull << 20));       // 8 MB  [b][h][t][d]
  unsigned short* k   = (unsigned short*)(ws + (23ull << 20));       // 8 MB  [b][h][t][d]
  unsigned short* vt  = (unsigned short*)(ws + (31ull << 20));       // 8 MB  [b][h][d][t]
  unsigned short* y   = (unsigned short*)(ws + (39ull << 20));       // 8 MB  [4096][1024]

  prep<<<7488, 256, 0, stream>>>(x, Wq, Wk, Wv, Wo, bo, xb, wqt, wkt, wvt, wot, out);
  qkv_gemm<<<dim3(32, 8, 3), 256, 0, stream>>>(xb, wqt, wkt, wvt, q, k, vt);
  attn9<<<dim3(32, 16), 256, 0, stream>>>(q, k, vt, y);
  oproj<<<dim3(64, 4), 256, 0, stream>>>(y, wot, out);
}